// Round 12
// baseline (12348.264 us; speedup 1.0000x reference)
//
#include <hip/hip_runtime.h>
#include <hip/hip_bf16.h>
#include <stdint.h>

#define BS 512
#define D 1024
#define H 4096
#define T_STEPS 64
#define N_INNER 4
#define SK 4

typedef __attribute__((ext_vector_type(8))) _Float16 f16x8;
typedef __attribute__((ext_vector_type(4))) float f32x4;
typedef __attribute__((ext_vector_type(4))) unsigned short u16x4;
typedef unsigned short u16;

__device__ __forceinline__ u16 f2h_bits(float f) {
    _Float16 h = (_Float16)f;
    return __builtin_bit_cast(u16, h);
}
__device__ __forceinline__ float h2f(u16 b) {
    return (float)__builtin_bit_cast(_Float16, b);
}
__device__ __forceinline__ float fast_tanh(float x) {
    float e = __expf(2.0f * x);
    return 1.0f - 2.0f / (e + 1.0f);
}

// ---------------- prep kernels ----------------

// src [rows][cols] f32 -> dst_hi/dst_lo [cols][rows] fp16 (hi + residual lo)
__global__ __launch_bounds__(256) void transpose_split(
    const float* __restrict__ src, u16* __restrict__ dst_hi,
    u16* __restrict__ dst_lo, int rows, int cols) {
    __shared__ float tile[32][33];
    const int tx = threadIdx.x & 31;
    const int ty = threadIdx.x >> 5;
    const int c0 = blockIdx.x * 32, r0 = blockIdx.y * 32;
    #pragma unroll
    for (int i = ty; i < 32; i += 8)
        tile[i][tx] = src[(size_t)(r0 + i) * cols + c0 + tx];
    __syncthreads();
    #pragma unroll
    for (int i = ty; i < 32; i += 8) {
        const float v = tile[tx][i];
        const u16 hi = f2h_bits(v);
        const u16 lo = f2h_bits(v - h2f(hi));
        const size_t idx = (size_t)(c0 + i) * rows + r0 + tx;
        dst_hi[idx] = hi;
        dst_lo[idx] = lo;
    }
}

__global__ __launch_bounds__(256) void init_z(
    const float* __restrict__ z0, float* __restrict__ z_cur,
    u16* __restrict__ z_h, float* __restrict__ out) {
    const int i = blockIdx.x * 256 + threadIdx.x;
    const float v = z0[i];
    z_cur[i] = v;
    z_h[i] = f2h_bits(v);
    out[i] = v;
}

// ---------------- B staging (rule #21 swizzle, r4/r10-proven) ----------------
// 64x64 fp16 tile (128 B rows): linear LDS dest, inverse-swizzled global src.
// 2 global_load_lds per thread (= 2 per-wave vmcnt events).
__device__ __forceinline__ void stage_one(
    const u16* __restrict__ src, u16* lds, int row0, int ldK, int k0, int tid) {
    #pragma unroll
    for (int i = 0; i < 2; ++i) {
        const int L = (i * 256 + tid) * 16;        // byte offset in tile
        const int r = L >> 7;
        const int cb = (L & 127) ^ ((r & 7) << 4);
        const size_t goff = (size_t)(row0 + r) * ldK + k0 + (cb >> 1);
        const int ldsoff = (i * 256 + (tid & ~63)) * 8;  // elems, wave-uniform
        __builtin_amdgcn_global_load_lds(
            (const __attribute__((address_space(1))) void*)(src + goff),
            (__attribute__((address_space(3))) void*)(lds + ldsoff), 16, 0, 0);
    }
}

// ---------------- fused fp16 GEMM: A direct-from-L2, B LDS depth-3 ----------
// (r10 structure; ONLY change = A from LDS -> direct global gather.)
// C = A[M][K] @ BT[N][K]^T ; A single fp16 (registers), B split hi/lo.
// 64x64 tile, BK=64, 16 K-iters, 4 waves (2x2) of 32x32.
// Per iter: issue 4 A-gathers -> vmcnt(8) [B-stage kt landed; stage kt+1 +
// A(kt) in flight] -> s_barrier -> issue B-stage kt+2 -> ds_read B + MFMA.
// EPI==0: GEMM1 (K=1024, N=4096): hid = tanh(C+b1) fp16.
// EPI==1: GEMM2 split-K (4 x K=1024, N=1024): fp32 partials (plain stores;
//         coherence via dispatch boundary, r10-proven).
template<int EPI>
__global__ __launch_bounds__(256, 2) void gemm_step(
    const u16* __restrict__ A_h,
    const u16* __restrict__ B_hi, const u16* __restrict__ B_lo,
    const float* __restrict__ bias,
    u16* __restrict__ hid_out,
    float* __restrict__ part) {
    __shared__ __align__(16) u16 lBh[3][4096];
    __shared__ __align__(16) u16 lBl[3][4096];

    const int tid = threadIdx.x;
    const int bid = blockIdx.x;
    const int xcd = bid & 7, loc = bid >> 3;
    int tm, tn, sk, ldK;
    if (EPI == 0) {       // 8 tm x 64 tn; XCD owns 8 consecutive tn
        tn = xcd * 8 + (loc & 7);
        tm = loc >> 3;
        sk = 0;  ldK = D;
    } else {              // 4 sk x 8 tm x 16 tn; XCD owns 2 consecutive tn
        tn = xcd * 2 + (loc & 1);
        tm = (loc >> 1) & 7;
        sk = loc >> 4;  ldK = H;
    }
    const int m0 = tm * 64, n0 = tn * 64;
    const int k0b = sk * 1024;

    const int wave = tid >> 6;
    const int lane = tid & 63;
    const int wr = wave >> 1, wc = wave & 1;
    const int l15 = lane & 15;
    const int lgrp = lane >> 4;
    const int lk8 = lgrp * 8;

    // A row base pointers for this lane's two fragment rows
    const u16* arow0 = A_h + (size_t)(m0 + wr * 32 + l15) * ldK + lk8;
    const u16* arow1 = A_h + (size_t)(m0 + wr * 32 + 16 + l15) * ldK + lk8;

    f32x4 acc[2][2];
    #pragma unroll
    for (int mi = 0; mi < 2; ++mi)
        #pragma unroll
        for (int ni = 0; ni < 2; ++ni)
            acc[mi][ni] = (f32x4){0.f, 0.f, 0.f, 0.f};

    auto STAGE = [&](int buf, int kt) {
        const int k0 = k0b + kt * 64;
        stage_one(B_hi, lBh[buf], n0, ldK, k0, tid);
        stage_one(B_lo, lBl[buf], n0, ldK, k0, tid);   // 4 loads/wave
    };

    STAGE(0, 0);
    STAGE(1, 1);
    int cur = 0;
    for (int kt = 0; kt < 16; ++kt) {
        // A gathers for this kt: L2-hot rows; latency overlaps the
        // barrier + ds_read window. 16B/lane, 16B-aligned.
        const int ka = k0b + kt * 64;
        f16x8 a00 = *(const f16x8*)(arow0 + ka);        // kk=0,  mi=0
        f16x8 a01 = *(const f16x8*)(arow1 + ka);        // kk=0,  mi=1
        f16x8 a10 = *(const f16x8*)(arow0 + ka + 32);   // kk=32, mi=0
        f16x8 a11 = *(const f16x8*)(arow1 + ka + 32);   // kk=32, mi=1

        if (kt < 15) asm volatile("s_waitcnt vmcnt(8)" ::: "memory");
        else         asm volatile("s_waitcnt vmcnt(4)" ::: "memory");
        asm volatile("s_barrier" ::: "memory");
        if (kt < 14) {
            int nb = cur + 2; if (nb >= 3) nb -= 3;
            STAGE(nb, kt + 2);
        }

        const char* Bh = (const char*)lBh[cur];
        const char* Bl = (const char*)lBl[cur];
        #pragma unroll
        for (int kki = 0; kki < 2; ++kki) {
            const int kk = kki * 32;
            f16x8 bfh[2], bfl[2];
            #pragma unroll
            for (int ni = 0; ni < 2; ++ni) {
                const int row = wc * 32 + ni * 16 + l15;
                const int cb = ((kk + lk8) * 2) ^ ((row & 7) << 4);
                bfh[ni] = *(const f16x8*)(Bh + row * 128 + cb);
                bfl[ni] = *(const f16x8*)(Bl + row * 128 + cb);
            }
            const f16x8 af0 = kki ? a10 : a00;
            const f16x8 af1 = kki ? a11 : a01;
            #pragma unroll
            for (int ni = 0; ni < 2; ++ni) {
                acc[0][ni] = __builtin_amdgcn_mfma_f32_16x16x32_f16(
                    af0, bfh[ni], acc[0][ni], 0, 0, 0);
                acc[0][ni] = __builtin_amdgcn_mfma_f32_16x16x32_f16(
                    af0, bfl[ni], acc[0][ni], 0, 0, 0);
                acc[1][ni] = __builtin_amdgcn_mfma_f32_16x16x32_f16(
                    af1, bfh[ni], acc[1][ni], 0, 0, 0);
                acc[1][ni] = __builtin_amdgcn_mfma_f32_16x16x32_f16(
                    af1, bfl[ni], acc[1][ni], 0, 0, 0);
            }
        }
        ++cur; if (cur == 3) cur = 0;
    }

    // ---- epilogue (r10-identical) ----
    const int crow_base = m0 + wr * 32;
    const int ccol_base = n0 + wc * 32;
    if (EPI == 0) {
        #pragma unroll
        for (int mi = 0; mi < 2; ++mi)
            #pragma unroll
            for (int ni = 0; ni < 2; ++ni) {
                const int col = ccol_base + ni * 16 + l15;
                const float b = bias[col];
                #pragma unroll
                for (int r = 0; r < 4; ++r) {
                    const int row = crow_base + mi * 16 + lgrp * 4 + r;
                    const float v = fast_tanh(acc[mi][ni][r] + b);
                    hid_out[(size_t)row * H + col] = f2h_bits(v);
                }
            }
    } else {
        float* p = part + (size_t)sk * BS * D;
        #pragma unroll
        for (int mi = 0; mi < 2; ++mi)
            #pragma unroll
            for (int ni = 0; ni < 2; ++ni) {
                const int col = ccol_base + ni * 16 + l15;
                #pragma unroll
                for (int r = 0; r < 4; ++r) {
                    const int row = crow_base + mi * 16 + lgrp * 4 + r;
                    p[(size_t)row * D + col] = acc[mi][ni][r];
                }
            }
    }
}

// ---------------- split-K reduce + Euler update (r10-identical) --------------
__global__ __launch_bounds__(256) void reduce_update(
    const float* __restrict__ part, const float* __restrict__ b2,
    const float* __restrict__ z_in, float* __restrict__ z_out,
    u16* __restrict__ zh,
    float* __restrict__ traj, const float* __restrict__ tptr, int iv) {
    const int i = (blockIdx.x * 256 + threadIdx.x) * 4;
    const size_t SZ = (size_t)BS * D;
    const float4 p0 = *(const float4*)(part + i);
    const float4 p1 = *(const float4*)(part + SZ + i);
    const float4 p2 = *(const float4*)(part + 2 * SZ + i);
    const float4 p3 = *(const float4*)(part + 3 * SZ + i);
    const float4 b  = *(const float4*)(b2 + (i & (D - 1)));
    const float4 z  = *(const float4*)(z_in + i);
    const float h = fabsf(tptr[iv + 1] - tptr[iv]) * (1.0f / N_INNER);
    float4 v;
    v.x = z.x + h * (p0.x + p1.x + p2.x + p3.x + b.x);
    v.y = z.y + h * (p0.y + p1.y + p2.y + p3.y + b.y);
    v.z = z.z + h * (p0.z + p1.z + p2.z + p3.z + b.z);
    v.w = z.w + h * (p0.w + p1.w + p2.w + p3.w + b.w);
    *(float4*)(z_out + i) = v;
    u16x4 h4;
    h4.x = f2h_bits(v.x);
    h4.y = f2h_bits(v.y);
    h4.z = f2h_bits(v.z);
    h4.w = f2h_bits(v.w);
    *(u16x4*)(zh + i) = h4;
    if (traj) *(float4*)(traj + i) = v;
}

// ---------------- host ----------------

extern "C" void kernel_launch(void* const* d_in, const int* in_sizes, int n_in,
                              void* d_out, int out_size, void* d_ws, size_t ws_size,
                              hipStream_t stream) {
    const float* z0 = (const float*)d_in[0];
    const float* t  = (const float*)d_in[1];
    const float* W1 = (const float*)d_in[2];
    const float* b1 = (const float*)d_in[3];
    const float* W2 = (const float*)d_in[4];
    const float* b2 = (const float*)d_in[5];
    float* out = (float*)d_out;

    char* ws = (char*)d_ws;
    u16*   W1T_hi = (u16*)(ws);                        // [H][D] fp16, 8 MB
    u16*   W1T_lo = (u16*)(ws + (8u << 20));
    u16*   W2T_hi = (u16*)(ws + (16u << 20));          // [D][H] fp16, 8 MB
    u16*   W2T_lo = (u16*)(ws + (24u << 20));
    float* z_cur  = (float*)(ws + (32u << 20));        // [BS][D] f32
    u16*   z_h    = (u16*)(ws + (34u << 20));          // [BS][D] fp16
    u16*   hid_h  = (u16*)(ws + (36u << 20));          // [BS][H] fp16
    float* part   = (float*)(ws + (44u << 20));        // SK x [BS][D] f32, 8 MB

    transpose_split<<<dim3(H / 32, D / 32), 256, 0, stream>>>(W1, W1T_hi, W1T_lo, D, H);
    transpose_split<<<dim3(D / 32, H / 32), 256, 0, stream>>>(W2, W2T_hi, W2T_lo, H, D);
    init_z<<<(BS * D) / 256, 256, 0, stream>>>(z0, z_cur, z_h, out);

    for (int iv = 0; iv < T_STEPS - 1; ++iv) {
        for (int s = 0; s < N_INNER; ++s) {
            gemm_step<0><<<512, 256, 0, stream>>>(
                z_h, W1T_hi, W1T_lo, b1, hid_h, nullptr);
            gemm_step<1><<<512, 256, 0, stream>>>(
                hid_h, W2T_hi, W2T_lo, nullptr, nullptr, part);
            float* traj = (s == N_INNER - 1) ? out + (size_t)(iv + 1) * BS * D : nullptr;
            reduce_update<<<512, 256, 0, stream>>>(
                part, b2, z_cur, z_cur, z_h, traj, t, iv);
        }
    }
}